// Round 15
// baseline (84.302 us; speedup 1.0000x reference)
//
#include <hip/hip_runtime.h>
#include <hip/hip_bf16.h>
#include <math.h>

// GAT: out = softmax(mask(lrelu(w1 + w2^T), adj)) @ (x@W) + bias
// R15 = R14 with B-dbuf dropped (B-frags are L2-resident; issue grouped
// early instead) to fit __launch_bounds__(256,4): 16 waves/CU -> +33%
// outstanding adj bytes (Little's-law shortfall was the R14 excess theory).
// Keeps: issue-first adj double-buffer, setprio, 2 A-tiles/wave sharing B.

#define NN    8192
#define INF   256
#define OUTF  64
#define TILE1 16
#define BM    128
#define SPL   16
#define CPS   (NN / SPL)    // 512
#define NT    (CPS / 32)    // 16
#define C0    1.0000900040501013f   // expf(9e-5)
#define LOG2E 1.4426950408889634f

typedef __bf16 bf16x8 __attribute__((ext_vector_type(8)));
typedef float  f32x4  __attribute__((ext_vector_type(4)));
typedef int    i32x4  __attribute__((ext_vector_type(4)));

// k1: Wh = x@W; row/col softmax factors e=exp(w), f=exp(0.2w); WhTt tiled bf16
__global__ __launch_bounds__(256) void k1_proj(
    const float* __restrict__ x, const float* __restrict__ W,
    const float* __restrict__ alpha, __bf16* __restrict__ WhTt,
    float* __restrict__ e1, float* __restrict__ f1,
    float* __restrict__ e2, float* __restrict__ f2)
{
    __shared__ float xs[TILE1 * INF];
    __shared__ float shwh[TILE1 * 65];
    const int tid = threadIdx.x;
    const int i0 = blockIdx.x * TILE1;

    const float4* xsrc = (const float4*)(x + (size_t)i0 * INF);
    float4* xdst = (float4*)xs;
#pragma unroll
    for (int it = 0; it < (TILE1 * INF / 4) / 256; ++it)
        xdst[tid + it * 256] = xsrc[tid + it * 256];
    __syncthreads();

    const int wave = tid >> 6, lane = tid & 63;
    const float a1 = alpha[lane], a2 = alpha[OUTF + lane];
    const int ilbase = wave * 4;

    float acc[4] = {};
#pragma unroll 4
    for (int k4 = 0; k4 < INF / 4; ++k4) {
        float wk0 = W[(4 * k4 + 0) * OUTF + lane];
        float wk1 = W[(4 * k4 + 1) * OUTF + lane];
        float wk2 = W[(4 * k4 + 2) * OUTF + lane];
        float wk3 = W[(4 * k4 + 3) * OUTF + lane];
#pragma unroll
        for (int rr = 0; rr < 4; ++rr) {
            float4 xv = *(const float4*)&xs[(ilbase + rr) * INF + 4 * k4];
            acc[rr] = fmaf(xv.x, wk0, acc[rr]);
            acc[rr] = fmaf(xv.y, wk1, acc[rr]);
            acc[rr] = fmaf(xv.z, wk2, acc[rr]);
            acc[rr] = fmaf(xv.w, wk3, acc[rr]);
        }
    }

#pragma unroll
    for (int rr = 0; rr < 4; ++rr) {
        const int il = ilbase + rr;
        const int i  = i0 + il;
        float a = acc[rr];
        float v1 = a * a1, v2 = a * a2;
#pragma unroll
        for (int off = 32; off > 0; off >>= 1) {
            v1 += __shfl_xor(v1, off);
            v2 += __shfl_xor(v2, off);
        }
        if (lane == 0) {
            float v1L = v1 * LOG2E, v2L = v2 * LOG2E;
            e1[i] = exp2f(v1L); f1[i] = exp2f(0.2f * v1L);
            e2[i] = exp2f(v2L); f2[i] = exp2f(0.2f * v2L);
        }
        shwh[il * 65 + lane] = a;
    }
    __syncthreads();

#pragma unroll
    for (int it = 0; it < (OUTF * TILE1) / 256; ++it) {
        int idx = it * 256 + tid;
        int f = idx / TILE1, il = idx % TILE1;
        int j = i0 + il;
        WhTt[((size_t)(j >> 5) * 64 + f) * 32 + (j & 31)] = (__bf16)shwh[il * 65 + f];
    }
}

// k2: two A-tiles/wave share B-frags; adj dbuf only (B grouped-early, L2-hit).
__global__ __launch_bounds__(256, 4) void k2_attn(
    const int* __restrict__ adj,
    const float* __restrict__ e1g, const float* __restrict__ f1g,
    const float* __restrict__ e2g, const float* __restrict__ f2g,
    const __bf16* __restrict__ WhTt, float* __restrict__ pacc,
    float* __restrict__ pz)
{
    __shared__ float e2s[CPS], f2s[CPS];
    const int tid = threadIdx.x;
    const int s  = blockIdx.x % SPL;
    const int rt = blockIdx.x / SPL;
    const int jb = s * CPS;

#pragma unroll
    for (int i = 0; i < CPS / 256; ++i) {
        e2s[tid + 256 * i] = e2g[jb + tid + 256 * i];
        f2s[tid + 256 * i] = f2g[jb + tid + 256 * i];
    }
    __syncthreads();

    const int wave = tid >> 6, lane = tid & 63;
    const int fl = lane & 15, g = lane >> 4;
    const int rw0 = rt * BM + wave * 16;       // tile A rows rw0..rw0+15
    const int rowA = rw0 + fl;                 // tile B rows rw0+64..+79
    const float e1A = e1g[rowA], f1A = f1g[rowA];
    const float e1B = e1g[rowA + 64], f1B = f1g[rowA + 64];

    f32x4 aA0 = {}, aA1 = {}, aA2 = {}, aA3 = {}, aAZ = {};
    f32x4 aB0 = {}, aB1 = {}, aB2 = {}, aB3 = {}, aBZ = {};
    bf16x8 ones;
#pragma unroll
    for (int e = 0; e < 8; ++e) ones[e] = (__bf16)1.0f;

    const i32x4*  apA = (const i32x4*)(adj + (size_t)rowA * NN + jb) + 2 * g;
    const i32x4*  apB = apA + (size_t)64 * NN / 4;
    const __bf16* bb  = WhTt + (size_t)(jb >> 5) * 2048 + fl * 32 + g * 8;
    const float*  eb = e2s + 8 * g;
    const float*  fb = f2s + 8 * g;

    // prologue: stage adj tile 0
    i32x4 cA0 = apA[0], cA1 = apA[1], cB0 = apB[0], cB1 = apB[1];

#pragma unroll
    for (int t = 0; t < NT; ++t) {
        // issue next adj tile FIRST (stays in flight across P-build + MFMAs)
        i32x4 nA0, nA1, nB0, nB1;
        if (t + 1 < NT) {
            nA0 = apA[8 * (t + 1)]; nA1 = apA[8 * (t + 1) + 1];
            nB0 = apB[8 * (t + 1)]; nB1 = apB[8 * (t + 1) + 1];
        }
        // issue all 4 B-fragment loads early (L2-resident, ~200cy, covered
        // by P-build VALU + other waves)
        const __bf16* bt = bb + (size_t)t * 2048;
        bf16x8 b0 = *(const bf16x8*)(bt +    0);
        bf16x8 b1 = *(const bf16x8*)(bt +  512);
        bf16x8 b2 = *(const bf16x8*)(bt + 1024);
        bf16x8 b3 = *(const bf16x8*)(bt + 1536);

        const int co = 32 * t;
        float4 ee0 = *(const float4*)(eb + co), ee1 = *(const float4*)(eb + co + 4);
        float4 ff0 = *(const float4*)(fb + co), ff1 = *(const float4*)(fb + co + 4);

        int   aiA[8] = {cA0.x, cA0.y, cA0.z, cA0.w, cA1.x, cA1.y, cA1.z, cA1.w};
        int   aiB[8] = {cB0.x, cB0.y, cB0.z, cB0.w, cB1.x, cB1.y, cB1.z, cB1.w};
        float ev[8]  = {ee0.x, ee0.y, ee0.z, ee0.w, ee1.x, ee1.y, ee1.z, ee1.w};
        float fv[8]  = {ff0.x, ff0.y, ff0.z, ff0.w, ff1.x, ff1.y, ff1.z, ff1.w};

        bf16x8 paA, paB;
#pragma unroll
        for (int e = 0; e < 8; ++e) {
            float peA = fmaxf(e1A * ev[e], f1A * fv[e]);   // exp(lrelu(w1+w2))
            float peB = fmaxf(e1B * ev[e], f1B * fv[e]);
            paA[e] = (__bf16)((aiA[e] > 0) ? peA : C0);
            paB[e] = (__bf16)((aiB[e] > 0) ? peB : C0);
        }

        __builtin_amdgcn_s_setprio(1);
        aA0 = __builtin_amdgcn_mfma_f32_16x16x32_bf16(paA, b0, aA0, 0, 0, 0);
        aB0 = __builtin_amdgcn_mfma_f32_16x16x32_bf16(paB, b0, aB0, 0, 0, 0);
        aA1 = __builtin_amdgcn_mfma_f32_16x16x32_bf16(paA, b1, aA1, 0, 0, 0);
        aB1 = __builtin_amdgcn_mfma_f32_16x16x32_bf16(paB, b1, aB1, 0, 0, 0);
        aA2 = __builtin_amdgcn_mfma_f32_16x16x32_bf16(paA, b2, aA2, 0, 0, 0);
        aB2 = __builtin_amdgcn_mfma_f32_16x16x32_bf16(paB, b2, aB2, 0, 0, 0);
        aA3 = __builtin_amdgcn_mfma_f32_16x16x32_bf16(paA, b3, aA3, 0, 0, 0);
        aB3 = __builtin_amdgcn_mfma_f32_16x16x32_bf16(paB, b3, aB3, 0, 0, 0);
        aAZ = __builtin_amdgcn_mfma_f32_16x16x32_bf16(paA, ones, aAZ, 0, 0, 0);
        aBZ = __builtin_amdgcn_mfma_f32_16x16x32_bf16(paB, ones, aBZ, 0, 0, 0);
        __builtin_amdgcn_s_setprio(0);

        if (t + 1 < NT) { cA0 = nA0; cA1 = nA1; cB0 = nB0; cB1 = nB1; }
    }

    if (fl == 0) {
#pragma unroll
        for (int i = 0; i < 4; ++i) {
            pz[(size_t)s * NN + rw0 + 4 * g + i]      = aAZ[i];
            pz[(size_t)s * NN + rw0 + 64 + 4 * g + i] = aBZ[i];
        }
    }
    float* prA = pacc + ((size_t)s * NN + rw0 + 4 * g) * OUTF + fl;
    float* prB = prA + (size_t)64 * OUTF;
#pragma unroll
    for (int i = 0; i < 4; ++i) {
        __builtin_nontemporal_store(aA0[i], prA + (size_t)i * OUTF + 0);
        __builtin_nontemporal_store(aA1[i], prA + (size_t)i * OUTF + 16);
        __builtin_nontemporal_store(aA2[i], prA + (size_t)i * OUTF + 32);
        __builtin_nontemporal_store(aA3[i], prA + (size_t)i * OUTF + 48);
        __builtin_nontemporal_store(aB0[i], prB + (size_t)i * OUTF + 0);
        __builtin_nontemporal_store(aB1[i], prB + (size_t)i * OUTF + 16);
        __builtin_nontemporal_store(aB2[i], prB + (size_t)i * OUTF + 32);
        __builtin_nontemporal_store(aB3[i], prB + (size_t)i * OUTF + 48);
    }
}

// k3: combine splits, divide by Z, add bias
__global__ __launch_bounds__(256) void k3_final(
    const float* __restrict__ pacc, const float* __restrict__ pz,
    const float* __restrict__ bias, float* __restrict__ out)
{
    const int t = blockIdx.x * 256 + threadIdx.x;
    const int i = t >> 6, f = t & 63;
    float num = 0.f, z = 0.f;
#pragma unroll
    for (int s = 0; s < SPL; ++s) {
        num += pacc[(size_t)s * NN * OUTF + t];
        z   += pz[(size_t)s * NN + i];
    }
    out[t] = num / z + bias[f];
}

extern "C" void kernel_launch(void* const* d_in, const int* in_sizes, int n_in,
                              void* d_out, int out_size, void* d_ws, size_t ws_size,
                              hipStream_t stream)
{
    const float* x     = (const float*)d_in[0];
    const int*   adj   = (const int*)d_in[1];
    const float* W     = (const float*)d_in[2];
    const float* alpha = (const float*)d_in[3];
    const float* bias  = (const float*)d_in[4];
    float* out = (float*)d_out;

    char* ws = (char*)d_ws;
    size_t off = 0;
    __bf16* WhTt = (__bf16*)(ws + off); off += (size_t)NN * OUTF * 2;
    float* e1 = (float*)(ws + off); off += (size_t)NN * 4;
    float* f1 = (float*)(ws + off); off += (size_t)NN * 4;
    float* e2 = (float*)(ws + off); off += (size_t)NN * 4;
    float* f2 = (float*)(ws + off); off += (size_t)NN * 4;
    float* pz = (float*)(ws + off);  off += (size_t)SPL * NN * 4;
    float* pacc = (float*)(ws + off); off += (size_t)SPL * NN * OUTF * 4;

    k1_proj<<<NN / TILE1, 256, 0, stream>>>(x, W, alpha, WhTt, e1, f1, e2, f2);
    k2_attn<<<(NN / BM) * SPL, 256, 0, stream>>>(adj, e1, f1, e2, f2, WhTt, pacc, pz);
    k3_final<<<(NN * OUTF) / 256, 256, 0, stream>>>(pacc, pz, bias, out);
}

// Round 16
// 80.934 us; speedup vs baseline: 1.0416x; 1.0416x over previous
//
#include <hip/hip_runtime.h>
#include <hip/hip_bf16.h>
#include <math.h>

// GAT: out = softmax(mask(lrelu(w1 + w2^T), adj)) @ (x@W) + bias
// R16 = exact revert to R14 (best measured: 81.3us). R15's B-dbuf removal
// regressed (-3.6%). Structure: issue-first double-buffer of adj+B frags,
// setprio around MFMA cluster, two 16-row A-tiles per wave sharing B-frags,
// factorized exp (P = mask ? max(e1*e2, f1*f2) : C0), fp32 partials.

#define NN    8192
#define INF   256
#define OUTF  64
#define TILE1 16
#define BM    128
#define SPL   16
#define CPS   (NN / SPL)    // 512
#define NT    (CPS / 32)    // 16
#define C0    1.0000900040501013f   // expf(9e-5)
#define LOG2E 1.4426950408889634f

typedef __bf16 bf16x8 __attribute__((ext_vector_type(8)));
typedef float  f32x4  __attribute__((ext_vector_type(4)));
typedef int    i32x4  __attribute__((ext_vector_type(4)));

// k1: Wh = x@W; row/col softmax factors e=exp(w), f=exp(0.2w); WhTt tiled bf16
__global__ __launch_bounds__(256) void k1_proj(
    const float* __restrict__ x, const float* __restrict__ W,
    const float* __restrict__ alpha, __bf16* __restrict__ WhTt,
    float* __restrict__ e1, float* __restrict__ f1,
    float* __restrict__ e2, float* __restrict__ f2)
{
    __shared__ float xs[TILE1 * INF];
    __shared__ float shwh[TILE1 * 65];
    const int tid = threadIdx.x;
    const int i0 = blockIdx.x * TILE1;

    const float4* xsrc = (const float4*)(x + (size_t)i0 * INF);
    float4* xdst = (float4*)xs;
#pragma unroll
    for (int it = 0; it < (TILE1 * INF / 4) / 256; ++it)
        xdst[tid + it * 256] = xsrc[tid + it * 256];
    __syncthreads();

    const int wave = tid >> 6, lane = tid & 63;
    const float a1 = alpha[lane], a2 = alpha[OUTF + lane];
    const int ilbase = wave * 4;

    float acc[4] = {};
#pragma unroll 4
    for (int k4 = 0; k4 < INF / 4; ++k4) {
        float wk0 = W[(4 * k4 + 0) * OUTF + lane];
        float wk1 = W[(4 * k4 + 1) * OUTF + lane];
        float wk2 = W[(4 * k4 + 2) * OUTF + lane];
        float wk3 = W[(4 * k4 + 3) * OUTF + lane];
#pragma unroll
        for (int rr = 0; rr < 4; ++rr) {
            float4 xv = *(const float4*)&xs[(ilbase + rr) * INF + 4 * k4];
            acc[rr] = fmaf(xv.x, wk0, acc[rr]);
            acc[rr] = fmaf(xv.y, wk1, acc[rr]);
            acc[rr] = fmaf(xv.z, wk2, acc[rr]);
            acc[rr] = fmaf(xv.w, wk3, acc[rr]);
        }
    }

#pragma unroll
    for (int rr = 0; rr < 4; ++rr) {
        const int il = ilbase + rr;
        const int i  = i0 + il;
        float a = acc[rr];
        float v1 = a * a1, v2 = a * a2;
#pragma unroll
        for (int off = 32; off > 0; off >>= 1) {
            v1 += __shfl_xor(v1, off);
            v2 += __shfl_xor(v2, off);
        }
        if (lane == 0) {
            float v1L = v1 * LOG2E, v2L = v2 * LOG2E;
            e1[i] = exp2f(v1L); f1[i] = exp2f(0.2f * v1L);
            e2[i] = exp2f(v2L); f2[i] = exp2f(0.2f * v2L);
        }
        shwh[il * 65 + lane] = a;
    }
    __syncthreads();

#pragma unroll
    for (int it = 0; it < (OUTF * TILE1) / 256; ++it) {
        int idx = it * 256 + tid;
        int f = idx / TILE1, il = idx % TILE1;
        int j = i0 + il;
        WhTt[((size_t)(j >> 5) * 64 + f) * 32 + (j & 31)] = (__bf16)shwh[il * 65 + f];
    }
}

// k2: two A-tiles/wave share B-frags; dbl-buffered adj+B; 8+2 MFMAs/iter.
__global__ __launch_bounds__(256, 3) void k2_attn(
    const int* __restrict__ adj,
    const float* __restrict__ e1g, const float* __restrict__ f1g,
    const float* __restrict__ e2g, const float* __restrict__ f2g,
    const __bf16* __restrict__ WhTt, float* __restrict__ pacc,
    float* __restrict__ pz)
{
    __shared__ float e2s[CPS], f2s[CPS];
    const int tid = threadIdx.x;
    const int s  = blockIdx.x % SPL;
    const int rt = blockIdx.x / SPL;
    const int jb = s * CPS;

#pragma unroll
    for (int i = 0; i < CPS / 256; ++i) {
        e2s[tid + 256 * i] = e2g[jb + tid + 256 * i];
        f2s[tid + 256 * i] = f2g[jb + tid + 256 * i];
    }
    __syncthreads();

    const int wave = tid >> 6, lane = tid & 63;
    const int fl = lane & 15, g = lane >> 4;
    const int rw0 = rt * BM + wave * 16;       // tile A rows rw0..rw0+15
    const int rowA = rw0 + fl;                 // tile B rows rw0+64..+79
    const float e1A = e1g[rowA], f1A = f1g[rowA];
    const float e1B = e1g[rowA + 64], f1B = f1g[rowA + 64];

    f32x4 aA0 = {}, aA1 = {}, aA2 = {}, aA3 = {}, aAZ = {};
    f32x4 aB0 = {}, aB1 = {}, aB2 = {}, aB3 = {}, aBZ = {};
    bf16x8 ones;
#pragma unroll
    for (int e = 0; e < 8; ++e) ones[e] = (__bf16)1.0f;

    const i32x4*  apA = (const i32x4*)(adj + (size_t)rowA * NN + jb) + 2 * g;
    const i32x4*  apB = apA + (size_t)64 * NN / 4;
    const __bf16* bb  = WhTt + (size_t)(jb >> 5) * 2048 + fl * 32 + g * 8;
    const float*  eb = e2s + 8 * g;
    const float*  fb = f2s + 8 * g;

    // prologue: stage tile 0 (adj + B fragments)
    i32x4 cA0 = apA[0], cA1 = apA[1], cB0 = apB[0], cB1 = apB[1];
    bf16x8 cb0 = *(const bf16x8*)(bb +    0);
    bf16x8 cb1 = *(const bf16x8*)(bb +  512);
    bf16x8 cb2 = *(const bf16x8*)(bb + 1024);
    bf16x8 cb3 = *(const bf16x8*)(bb + 1536);

#pragma unroll
    for (int t = 0; t < NT; ++t) {
        // stage t+1 FIRST (issue-before-consume: stays in flight across
        // this iter's P-build + MFMAs)
        i32x4 nA0, nA1, nB0, nB1;
        bf16x8 nb0, nb1, nb2, nb3;
        if (t + 1 < NT) {
            nA0 = apA[8 * (t + 1)]; nA1 = apA[8 * (t + 1) + 1];
            nB0 = apB[8 * (t + 1)]; nB1 = apB[8 * (t + 1) + 1];
            const __bf16* btn = bb + (size_t)(t + 1) * 2048;
            nb0 = *(const bf16x8*)(btn +    0);
            nb1 = *(const bf16x8*)(btn +  512);
            nb2 = *(const bf16x8*)(btn + 1024);
            nb3 = *(const bf16x8*)(btn + 1536);
        }

        const int co = 32 * t;
        float4 ee0 = *(const float4*)(eb + co), ee1 = *(const float4*)(eb + co + 4);
        float4 ff0 = *(const float4*)(fb + co), ff1 = *(const float4*)(fb + co + 4);

        int   aiA[8] = {cA0.x, cA0.y, cA0.z, cA0.w, cA1.x, cA1.y, cA1.z, cA1.w};
        int   aiB[8] = {cB0.x, cB0.y, cB0.z, cB0.w, cB1.x, cB1.y, cB1.z, cB1.w};
        float ev[8]  = {ee0.x, ee0.y, ee0.z, ee0.w, ee1.x, ee1.y, ee1.z, ee1.w};
        float fv[8]  = {ff0.x, ff0.y, ff0.z, ff0.w, ff1.x, ff1.y, ff1.z, ff1.w};

        bf16x8 paA, paB;
#pragma unroll
        for (int e = 0; e < 8; ++e) {
            float peA = fmaxf(e1A * ev[e], f1A * fv[e]);   // exp(lrelu(w1+w2))
            float peB = fmaxf(e1B * ev[e], f1B * fv[e]);
            paA[e] = (__bf16)((aiA[e] > 0) ? peA : C0);
            paB[e] = (__bf16)((aiB[e] > 0) ? peB : C0);
        }

        __builtin_amdgcn_s_setprio(1);
        aA0 = __builtin_amdgcn_mfma_f32_16x16x32_bf16(paA, cb0, aA0, 0, 0, 0);
        aB0 = __builtin_amdgcn_mfma_f32_16x16x32_bf16(paB, cb0, aB0, 0, 0, 0);
        aA1 = __builtin_amdgcn_mfma_f32_16x16x32_bf16(paA, cb1, aA1, 0, 0, 0);
        aB1 = __builtin_amdgcn_mfma_f32_16x16x32_bf16(paB, cb1, aB1, 0, 0, 0);
        aA2 = __builtin_amdgcn_mfma_f32_16x16x32_bf16(paA, cb2, aA2, 0, 0, 0);
        aB2 = __builtin_amdgcn_mfma_f32_16x16x32_bf16(paB, cb2, aB2, 0, 0, 0);
        aA3 = __builtin_amdgcn_mfma_f32_16x16x32_bf16(paA, cb3, aA3, 0, 0, 0);
        aB3 = __builtin_amdgcn_mfma_f32_16x16x32_bf16(paB, cb3, aB3, 0, 0, 0);
        aAZ = __builtin_amdgcn_mfma_f32_16x16x32_bf16(paA, ones, aAZ, 0, 0, 0);
        aBZ = __builtin_amdgcn_mfma_f32_16x16x32_bf16(paB, ones, aBZ, 0, 0, 0);
        __builtin_amdgcn_s_setprio(0);

        if (t + 1 < NT) {
            cA0 = nA0; cA1 = nA1; cB0 = nB0; cB1 = nB1;
            cb0 = nb0; cb1 = nb1; cb2 = nb2; cb3 = nb3;
        }
    }

    if (fl == 0) {
#pragma unroll
        for (int i = 0; i < 4; ++i) {
            pz[(size_t)s * NN + rw0 + 4 * g + i]      = aAZ[i];
            pz[(size_t)s * NN + rw0 + 64 + 4 * g + i] = aBZ[i];
        }
    }
    float* prA = pacc + ((size_t)s * NN + rw0 + 4 * g) * OUTF + fl;
    float* prB = prA + (size_t)64 * OUTF;
#pragma unroll
    for (int i = 0; i < 4; ++i) {
        __builtin_nontemporal_store(aA0[i], prA + (size_t)i * OUTF + 0);
        __builtin_nontemporal_store(aA1[i], prA + (size_t)i * OUTF + 16);
        __builtin_nontemporal_store(aA2[i], prA + (size_t)i * OUTF + 32);
        __builtin_nontemporal_store(aA3[i], prA + (size_t)i * OUTF + 48);
        __builtin_nontemporal_store(aB0[i], prB + (size_t)i * OUTF + 0);
        __builtin_nontemporal_store(aB1[i], prB + (size_t)i * OUTF + 16);
        __builtin_nontemporal_store(aB2[i], prB + (size_t)i * OUTF + 32);
        __builtin_nontemporal_store(aB3[i], prB + (size_t)i * OUTF + 48);
    }
}

// k3: combine splits, divide by Z, add bias
__global__ __launch_bounds__(256) void k3_final(
    const float* __restrict__ pacc, const float* __restrict__ pz,
    const float* __restrict__ bias, float* __restrict__ out)
{
    const int t = blockIdx.x * 256 + threadIdx.x;
    const int i = t >> 6, f = t & 63;
    float num = 0.f, z = 0.f;
#pragma unroll
    for (int s = 0; s < SPL; ++s) {
        num += pacc[(size_t)s * NN * OUTF + t];
        z   += pz[(size_t)s * NN + i];
    }
    out[t] = num / z + bias[f];
}

extern "C" void kernel_launch(void* const* d_in, const int* in_sizes, int n_in,
                              void* d_out, int out_size, void* d_ws, size_t ws_size,
                              hipStream_t stream)
{
    const float* x     = (const float*)d_in[0];
    const int*   adj   = (const int*)d_in[1];
    const float* W     = (const float*)d_in[2];
    const float* alpha = (const float*)d_in[3];
    const float* bias  = (const float*)d_in[4];
    float* out = (float*)d_out;

    char* ws = (char*)d_ws;
    size_t off = 0;
    __bf16* WhTt = (__bf16*)(ws + off); off += (size_t)NN * OUTF * 2;
    float* e1 = (float*)(ws + off); off += (size_t)NN * 4;
    float* f1 = (float*)(ws + off); off += (size_t)NN * 4;
    float* e2 = (float*)(ws + off); off += (size_t)NN * 4;
    float* f2 = (float*)(ws + off); off += (size_t)NN * 4;
    float* pz = (float*)(ws + off);  off += (size_t)SPL * NN * 4;
    float* pacc = (float*)(ws + off); off += (size_t)SPL * NN * OUTF * 4;

    k1_proj<<<NN / TILE1, 256, 0, stream>>>(x, W, alpha, WhTt, e1, f1, e2, f2);
    k2_attn<<<(NN / BM) * SPL, 256, 0, stream>>>(adj, e1, f1, e2, f2, WhTt, pacc, pz);
    k3_final<<<(NN * OUTF) / 256, 256, 0, stream>>>(pacc, pz, bias, out);
}